// Round 9
// baseline (820.980 us; speedup 1.0000x reference)
//
#include <hip/hip_runtime.h>

typedef __bf16 bf16x8 __attribute__((ext_vector_type(8)));
typedef float f32x4 __attribute__((ext_vector_type(4)));
typedef float f32x16 __attribute__((ext_vector_type(16)));
typedef _Float16 f16x2 __attribute__((ext_vector_type(2)));
typedef unsigned short u16x8 __attribute__((ext_vector_type(8)));
typedef unsigned int u32x4 __attribute__((ext_vector_type(4)));
typedef unsigned int u32x2 __attribute__((ext_vector_type(2)));

constexpr int C_ = 64, TD_ = 128, L_ = 4096, B_ = 2, H_ = 4, HD_ = 32;
// 32^-0.5 * log2(e): folded into Q at projection so softmax runs in base-2.
constexpr float SCALE_LOG2E = 0.25504821365f;

#if __has_builtin(__builtin_amdgcn_exp2f)
#define EXP2F __builtin_amdgcn_exp2f
#else
#define EXP2F exp2f
#endif

static __device__ __forceinline__ unsigned short f2bf(float f) {
  unsigned u = __builtin_bit_cast(unsigned, f);
  u += 0x7fffu + ((u >> 16) & 1u);  // RNE; inputs finite
  return (unsigned short)(u >> 16);
}
static __device__ __forceinline__ float bf2f(unsigned short h) {
  unsigned u = ((unsigned)h) << 16;
  return __builtin_bit_cast(float, u);
}
static __device__ __forceinline__ unsigned cvt_pk_bf16(float lo, float hi) {
  unsigned r;
  asm("v_cvt_pk_bf16_f32 %0, %1, %2" : "=v"(r) : "v"(lo), "v"(hi));
  return r;
}
// v_cvt_pkrtz_f16_f32: pack 2 f32 -> 2 f16 (RTZ); return raw u32 payload
static __device__ __forceinline__ unsigned cvt_pk_f16(float lo, float hi) {
  return __builtin_bit_cast(unsigned, __builtin_amdgcn_cvt_pkrtz(lo, hi));
}
static __device__ __forceinline__ void plane_swap(unsigned& a, unsigned& b) {
  asm("v_permlane32_swap_b32 %0, %1" : "+v"(a), "+v"(b));
}
static __device__ __forceinline__ float xhalf_add(float x) {
  float a = x, b = x;
  asm("v_permlane32_swap_b32 %0, %1" : "+v"(a), "+v"(b));
  return a + b;  // own + partner(lane^32), valid in all 64 lanes
}
// C/D row formula for 32x32 MFMA (m74/m101): row = (r&3)+8*(r>>2)+4*hi
static __device__ __forceinline__ int rowf(int r, int hi) {
  return (r & 3) + 8 * (r >> 2) + 4 * hi;
}
static __device__ __forceinline__ bf16x8 pack8(const float* v) {
  unsigned p0 = cvt_pk_bf16(v[0], v[1]);
  unsigned p1 = cvt_pk_bf16(v[2], v[3]);
  unsigned p2 = cvt_pk_bf16(v[4], v[5]);
  unsigned p3 = cvt_pk_bf16(v[6], v[7]);
  return __builtin_bit_cast(bf16x8, (u32x4){p0, p1, p2, p3});
}

// ---------------- projection v4: 3-way block split (unchanged, passing) -----
__global__ __launch_bounds__(256) void proj_kernel(
    const float* __restrict__ fct, const float* __restrict__ fpet,
    const float* __restrict__ wq, const float* __restrict__ bq,
    const float* __restrict__ wk, const float* __restrict__ bk,
    const float* __restrict__ wv, const float* __restrict__ bv,
    unsigned short* __restrict__ Qbf, unsigned short* __restrict__ Kbf,
    unsigned short* __restrict__ Vt, float* __restrict__ QT)
{
  __shared__ __align__(16) unsigned short Tb[32][136];  // 8.7 KB

  int bid = blockIdx.x;
  int lt = bid & 127;
  int rest = bid >> 7;     // 0..11
  int mb = rest & 3;
  int which = rest >> 2;   // 0=Q 1=K 2=V
  int l0 = lt * 32;
  int b = mb & 1;
  const float* xb = (mb >= 2 ? fpet : fct) + (size_t)b * C_ * L_;

  int lane = threadIdx.x & 63, wid = threadIdx.x >> 6;
  int l31 = lane & 31, hi = lane >> 5;
  int od = wid * 32;

  const float* W  = which == 0 ? wq : (which == 1 ? wk : wv);
  const float* Bs = which == 0 ? bq : (which == 1 ? bk : bv);

  const f32x16 Z = {0.f, 0.f, 0.f, 0.f, 0.f, 0.f, 0.f, 0.f,
                    0.f, 0.f, 0.f, 0.f, 0.f, 0.f, 0.f, 0.f};
  f32x16 acc = Z;
  #pragma unroll
  for (int ch = 0; ch < 4; ++ch) {
    float v[8], a[8];
    #pragma unroll
    for (int j = 0; j < 8; ++j)
      v[j] = xb[(size_t)(ch * 16 + hi * 8 + j) * L_ + l0 + l31];
    const float* wr = W + (size_t)(od + l31) * C_ + ch * 16 + hi * 8;
    #pragma unroll
    for (int j = 0; j < 8; ++j) a[j] = wr[j];
    acc = __builtin_amdgcn_mfma_f32_32x32x16_bf16(pack8(a), pack8(v), acc, 0, 0, 0);
  }

  if (which == 2) {
    #pragma unroll
    for (int r = 0; r < 16; ++r) {
      int o = od + rowf(r, hi);
      Vt[((size_t)mb * TD_ + o) * L_ + l0 + l31] = f2bf(acc[r] + Bs[o]);
    }
  } else {
    if (which == 0) {
      #pragma unroll
      for (int r = 0; r < 16; ++r) {
        int o = od + rowf(r, hi);
        QT[((size_t)mb * TD_ + o) * L_ + l0 + l31] = acc[r] + Bs[o];
      }
    }
    float sc = which == 0 ? SCALE_LOG2E : 1.0f;
    #pragma unroll
    for (int rg = 0; rg < 4; ++rg) {
      int cb = od + 8 * rg + 4 * hi;
      float y0 = (acc[rg * 4 + 0] + Bs[cb + 0]) * sc;
      float y1 = (acc[rg * 4 + 1] + Bs[cb + 1]) * sc;
      float y2 = (acc[rg * 4 + 2] + Bs[cb + 2]) * sc;
      float y3 = (acc[rg * 4 + 3] + Bs[cb + 3]) * sc;
      u32x2 pk = {cvt_pk_bf16(y0, y1), cvt_pk_bf16(y2, y3)};
      *(u32x2*)&Tb[l31][cb] = pk;
    }
    __syncthreads();
    unsigned short* dstg = which ? Kbf : Qbf;
    int row = threadIdx.x >> 3, chunk = threadIdx.x & 7;
    int h = chunk >> 1, d0 = (chunk & 1) * 16;
    u16x8 v0 = *(const u16x8*)&Tb[row][chunk * 16];
    u16x8 v1 = *(const u16x8*)&Tb[row][chunk * 16 + 8];
    size_t gb = (((size_t)mb * H_ + h) * L_ + l0 + row) * HD_ + d0;
    *(u16x8*)&dstg[gb] = v0;
    *(u16x8*)&dstg[gb + 8] = v1;
  }
}

// ---------------- flash cross-attention v7: 8-wave, 100%-occupancy ----------
// Max-free softmax; XCD-local mapping; depth-1 prefetch; 8-wave k-split
// (512 kk each) -> 32 waves/CU; fp16-packed merge; setprio on MFMA clusters.
static __device__ __forceinline__ void softmax_pv(
    const f32x16& S, float& lp, f32x16& O, bf16x8 vc0, bf16x8 vc1)
{
  float p[16];
  #pragma unroll
  for (int i = 0; i < 16; ++i) p[i] = EXP2F(S[i]);
  float s0 = (p[0] + p[1]) + (p[2] + p[3]);
  float s1 = (p[4] + p[5]) + (p[6] + p[7]);
  float s2 = (p[8] + p[9]) + (p[10] + p[11]);
  float s3 = (p[12] + p[13]) + (p[14] + p[15]);
  lp += (s0 + s1) + (s2 + s3);

  unsigned w0 = cvt_pk_bf16(p[0], p[1]);
  unsigned w1 = cvt_pk_bf16(p[2], p[3]);
  unsigned w2 = cvt_pk_bf16(p[4], p[5]);
  unsigned w3 = cvt_pk_bf16(p[6], p[7]);
  unsigned w4 = cvt_pk_bf16(p[8], p[9]);
  unsigned w5 = cvt_pk_bf16(p[10], p[11]);
  unsigned w6 = cvt_pk_bf16(p[12], p[13]);
  unsigned w7 = cvt_pk_bf16(p[14], p[15]);
  plane_swap(w0, w2);
  plane_swap(w1, w3);
  plane_swap(w4, w6);
  plane_swap(w5, w7);
  bf16x8 pf0 = __builtin_bit_cast(bf16x8, (u32x4){w0, w1, w2, w3});
  bf16x8 pf1 = __builtin_bit_cast(bf16x8, (u32x4){w4, w5, w6, w7});

  __builtin_amdgcn_s_setprio(1);
  O = __builtin_amdgcn_mfma_f32_32x32x16_bf16(vc0, pf0, O, 0, 0, 0);
  O = __builtin_amdgcn_mfma_f32_32x32x16_bf16(vc1, pf1, O, 0, 0, 0);
  __builtin_amdgcn_s_setprio(0);
}

__global__ __launch_bounds__(512, 8) void attn_kernel(
    const unsigned short* __restrict__ Qbf, const unsigned short* __restrict__ Kbf,
    const unsigned short* __restrict__ Vt, const float* __restrict__ QT,
    unsigned short* __restrict__ Fh, unsigned short* __restrict__ Fl)
{
  __shared__ __align__(16) unsigned Obuf[8][64][17];  // fp16x2 packs, 34.8 KB
  __shared__ float lbuf[8][64];                       // 2 KB

  int bid = blockIdx.x;
  int x = bid & 7, local = bid >> 3;
  int g = 2 * x + (local & 1);  // XCD x serves only head-groups {2x, 2x+1}
  int qg = local >> 1;          // 0..63
  int h = g & 3, b = (g >> 2) & 1, dir = g >> 3;

  int tid = threadIdx.x;
  int lane = tid & 63, wid = tid >> 6;  // wid 0..7
  int l31 = lane & 31, hi = lane >> 5;
  int q0 = qg * 64;
  int qmb = dir * B_ + b, kmb = (1 - dir) * B_ + b;
  int k0 = wid * 512;  // this wave's k-range (512 kk)

  // Q B-frags: direct bf16, pre-scaled at projection
  const unsigned short* qbase = Qbf + (size_t)(qmb * H_ + h) * L_ * HD_;
  bf16x8 qb[2][2];
  #pragma unroll
  for (int s = 0; s < 2; ++s)
    #pragma unroll
    for (int c = 0; c < 2; ++c)
      qb[s][c] = *(const bf16x8*)(qbase + (q0 + s * 32 + l31) * HD_ + c * 16 + hi * 8);

  const unsigned short* kp =
      Kbf + (size_t)(kmb * H_ + h) * L_ * HD_ + (k0 + l31) * HD_ + hi * 8;
  const unsigned short* vp =
      Vt + (size_t)(kmb * TD_ + h * HD_ + l31) * L_ + k0 + hi * 8;

  const f32x16 Z = {0.f, 0.f, 0.f, 0.f, 0.f, 0.f, 0.f, 0.f,
                    0.f, 0.f, 0.f, 0.f, 0.f, 0.f, 0.f, 0.f};
  f32x16 Oa[2] = {Z, Z};
  float lp[2] = {0.f, 0.f};

  bf16x8 kc0 = *(const bf16x8*)(kp);
  bf16x8 kc1 = *(const bf16x8*)(kp + 16);
  bf16x8 vc0 = *(const bf16x8*)(vp);
  bf16x8 vc1 = *(const bf16x8*)(vp + 16);

  #pragma unroll 4
  for (int t = 0; t < 16; ++t) {  // 16 tiles of 32 kk; depth-1 prefetch
    // prefetch t+1 (t=15 over-reads into adjacent ws region; discarded)
    bf16x8 kn0 = *(const bf16x8*)(kp + (t + 1) * 1024);
    bf16x8 kn1 = *(const bf16x8*)(kp + (t + 1) * 1024 + 16);
    bf16x8 vn0 = *(const bf16x8*)(vp + (t + 1) * 32);
    bf16x8 vn1 = *(const bf16x8*)(vp + (t + 1) * 32 + 16);
    #pragma unroll
    for (int s = 0; s < 2; ++s) {
      __builtin_amdgcn_s_setprio(1);
      f32x16 S = __builtin_amdgcn_mfma_f32_32x32x16_bf16(kc0, qb[s][0], Z, 0, 0, 0);
      S = __builtin_amdgcn_mfma_f32_32x32x16_bf16(kc1, qb[s][1], S, 0, 0, 0);
      __builtin_amdgcn_s_setprio(0);
      softmax_pv(S, lp[s], Oa[s], vc0, vc1);
    }
    kc0 = kn0; kc1 = kn1; vc0 = vn0; vc1 = vn1;
  }

  // ---- cross-wave merge, fp16-packed partials ----
  lp[0] = xhalf_add(lp[0]);
  lp[1] = xhalf_add(lp[1]);
  if (hi == 0) {
    lbuf[wid][l31] = lp[0];
    lbuf[wid][32 + l31] = lp[1];
  }
  #pragma unroll
  for (int s = 0; s < 2; ++s)
    #pragma unroll
    for (int r = 0; r < 16; r += 2) {  // even r: rowf(r+1)==rowf(r)+1
      unsigned pk2 = cvt_pk_f16(Oa[s][r], Oa[s][r + 1]);
      int d2 = ((r & 3) >> 1) + 4 * (r >> 2) + 2 * hi;
      Obuf[wid][s * 32 + l31][d2] = pk2;
    }
  __syncthreads();

  // 512 threads: token = tid&63, dgroup = tid>>6 -> 4 d-values each
  int token = tid & 63, dg = tid >> 6;
  float T = 0.f;
  #pragma unroll
  for (int w = 0; w < 8; ++w) T += lbuf[w][token];
  float inv = 1.0f / T;
  const float* qtp = QT + ((size_t)qmb * TD_ + h * HD_) * L_ + q0 + token;
  float vals[4];
  #pragma unroll
  for (int dp = 0; dp < 2; ++dp) {
    float se = 0.f, so = 0.f;
    #pragma unroll
    for (int w = 0; w < 8; ++w) {
      f16x2 v = __builtin_bit_cast(f16x2, Obuf[w][token][dg * 2 + dp]);
      se += (float)v[0];
      so += (float)v[1];
    }
    int dd = dg * 4 + dp * 2;
    vals[dp * 2]     = (se * inv + qtp[(size_t)dd * L_]) * 0.5f;
    vals[dp * 2 + 1] = (so * inv + qtp[(size_t)(dd + 1) * L_]) * 0.5f;
  }
  __syncthreads();

  // reuse Obuf[0..1] as bf16 hi/lo staging, then coalesced 16B stores
  unsigned (*Sb)[64][17] = (unsigned (*)[64][17])Obuf;
  #pragma unroll
  for (int dp = 0; dp < 2; ++dp) {
    float v0 = vals[dp * 2], v1 = vals[dp * 2 + 1];
    float h0 = bf2f(f2bf(v0)), h1 = bf2f(f2bf(v1));
    Sb[0][token][dg * 2 + dp] = cvt_pk_bf16(v0, v1);            // hi (RNE)
    Sb[1][token][dg * 2 + dp] = cvt_pk_bf16(v0 - h0, v1 - h1);  // lo residual
  }
  __syncthreads();
  int sel = tid >> 8, rem = tid & 255;  // 256 threads each for Fh, Fl
  int q = rem >> 2, dq = rem & 3;
  u32x4 v = *(const u32x4*)&Sb[sel][q][dq * 4];
  unsigned short* dst = sel ? Fl : Fh;
  *(u16x8*)&dst[((size_t)qmb * L_ + q0 + q) * TD_ + h * HD_ + dq * 8] =
      __builtin_bit_cast(u16x8, v);
}

// ---------------- epilogue v4 (unchanged, passing) ----------------
__global__ __launch_bounds__(256) void epi_kernel(
    const float* __restrict__ fct, const float* __restrict__ fpet,
    const float* __restrict__ wo, const float* __restrict__ bo,
    const unsigned short* __restrict__ Fh, const unsigned short* __restrict__ Fl,
    float* __restrict__ out)
{
  __shared__ __align__(16) unsigned short Gh[32][136], Gl[32][136];  // 17.4 KB
  __shared__ __align__(16) float red[2][32][33];                     // 8.4 KB

  int bid = blockIdx.x;
  int lt = bid & 127, im = bid >> 7;  // im = dir*B + b
  int b = im & 1, d = im >> 1;
  int l0 = lt * 32;
  int lr = l0 >> 7, col0 = l0 & 127;

  int tid = threadIdx.x;
  int lane = tid & 63, wid = tid >> 6;
  int l31 = lane & 31, hi = lane >> 5;
  int mt = wid & 1, kh = wid >> 1;
  int c0 = mt * 32;

  bf16x8 Ah[4], Al[4];
  #pragma unroll
  for (int ch = 0; ch < 4; ++ch) {
    const float* wr = wo + (size_t)(c0 + l31) * TD_ + (kh * 4 + ch) * 16 + hi * 8;
    float ah[8], al[8];
    #pragma unroll
    for (int j = 0; j < 8; ++j) {
      float v = wr[j];
      float hf = bf2f(f2bf(v));
      ah[j] = hf;
      al[j] = v - hf;
    }
    Ah[ch] = pack8(ah);
    Al[ch] = pack8(al);
  }

  {
    int o = tid & 127, half = tid >> 7;
    size_t src = ((size_t)im * L_ + o * 32 + lr) * TD_ + col0 + half * 16;
    u16x8 ha = *(const u16x8*)&Fh[src];
    u16x8 hb = *(const u16x8*)&Fh[src + 8];
    u16x8 la = *(const u16x8*)&Fl[src];
    u16x8 lb = *(const u16x8*)&Fl[src + 8];
    #pragma unroll
    for (int j = 0; j < 8; ++j) {
      Gh[half * 16 + j][o] = ha[j];
      Gl[half * 16 + j][o] = la[j];
    }
    #pragma unroll
    for (int j = 0; j < 8; ++j) {
      Gh[half * 16 + 8 + j][o] = hb[j];
      Gl[half * 16 + 8 + j][o] = lb[j];
    }
  }
  __syncthreads();

  const f32x16 Z = {0.f, 0.f, 0.f, 0.f, 0.f, 0.f, 0.f, 0.f,
                    0.f, 0.f, 0.f, 0.f, 0.f, 0.f, 0.f, 0.f};
  f32x16 acc = Z;
  #pragma unroll
  for (int ch = 0; ch < 4; ++ch) {
    int ko = (kh * 4 + ch) * 16 + hi * 8;
    bf16x8 Bh = *(const bf16x8*)&Gh[l31][ko];
    bf16x8 Bl = *(const bf16x8*)&Gl[l31][ko];
    acc = __builtin_amdgcn_mfma_f32_32x32x16_bf16(Ah[ch], Bh, acc, 0, 0, 0);
    acc = __builtin_amdgcn_mfma_f32_32x32x16_bf16(Ah[ch], Bl, acc, 0, 0, 0);
    acc = __builtin_amdgcn_mfma_f32_32x32x16_bf16(Al[ch], Bh, acc, 0, 0, 0);
  }

  if (kh == 1) {
    #pragma unroll
    for (int r = 0; r < 16; ++r) red[mt][rowf(r, hi)][l31] = acc[r];
  }
  __syncthreads();
  if (kh == 0) {
    const float* feat = (d ? fpet : fct) + (size_t)b * C_ * L_;
    float* ob = out + (size_t)im * C_ * L_;
    int l = l0 + l31;
    #pragma unroll
    for (int r = 0; r < 16; ++r) {
      int row = rowf(r, hi);
      int c = c0 + row;
      float v = acc[r] + red[mt][row][l31];
      ob[(size_t)c * L_ + l] = feat[(size_t)c * L_ + l] + bo[c] + v;
    }
  }
}

extern "C" void kernel_launch(void* const* d_in, const int* in_sizes, int n_in,
                              void* d_out, int out_size, void* d_ws, size_t ws_size,
                              hipStream_t stream)
{
  const float* fct  = (const float*)d_in[0];
  const float* fpet = (const float*)d_in[1];
  const float* wq = (const float*)d_in[2];
  const float* bq = (const float*)d_in[3];
  const float* wk = (const float*)d_in[4];
  const float* bk = (const float*)d_in[5];
  const float* wv = (const float*)d_in[6];
  const float* bv = (const float*)d_in[7];
  const float* wo = (const float*)d_in[8];
  const float* bo = (const float*)d_in[9];
  float* out = (float*)d_out;

  // ws: Qbf,Kbf,Vt (2M ushorts each, 12MB) + QT (2M f32, 8MB) + Fh,Fl (2M
  // ushorts each, 8MB) = 28MB
  unsigned short* Qbf = (unsigned short*)d_ws;
  unsigned short* Kbf = Qbf + 2097152;
  unsigned short* Vt  = Kbf + 2097152;
  float* QT = (float*)(Vt + 2097152);
  unsigned short* Fh = (unsigned short*)(QT + 2097152);
  unsigned short* Fl = Fh + 2097152;

  proj_kernel<<<1536, 256, 0, stream>>>(fct, fpet, wq, bq, wk, bk, wv, bv,
                                        Qbf, Kbf, Vt, QT);
  attn_kernel<<<1024, 512, 0, stream>>>(Qbf, Kbf, Vt, QT, Fh, Fl);
  epi_kernel<<<512, 256, 0, stream>>>(fct, fpet, wo, bo, Fh, Fl, out);
}

// Round 10
// 142.114 us; speedup vs baseline: 5.7769x; 5.7769x over previous
//
#include <hip/hip_runtime.h>

typedef __bf16 bf16x8 __attribute__((ext_vector_type(8)));
typedef float f32x2 __attribute__((ext_vector_type(2)));
typedef float f32x4 __attribute__((ext_vector_type(4)));
typedef float f32x16 __attribute__((ext_vector_type(16)));
typedef _Float16 f16x2 __attribute__((ext_vector_type(2)));
typedef unsigned short u16x8 __attribute__((ext_vector_type(8)));
typedef unsigned int u32x4 __attribute__((ext_vector_type(4)));
typedef unsigned int u32x2 __attribute__((ext_vector_type(2)));

constexpr int C_ = 64, TD_ = 128, L_ = 4096, B_ = 2, H_ = 4, HD_ = 32;
// 32^-0.5 * log2(e): folded into Q at projection so softmax runs in base-2.
constexpr float SCALE_LOG2E = 0.25504821365f;

#if __has_builtin(__builtin_amdgcn_exp2f)
#define EXP2F __builtin_amdgcn_exp2f
#else
#define EXP2F exp2f
#endif

static __device__ __forceinline__ unsigned short f2bf(float f) {
  unsigned u = __builtin_bit_cast(unsigned, f);
  u += 0x7fffu + ((u >> 16) & 1u);  // RNE; inputs finite
  return (unsigned short)(u >> 16);
}
static __device__ __forceinline__ float bf2f(unsigned short h) {
  unsigned u = ((unsigned)h) << 16;
  return __builtin_bit_cast(float, u);
}
static __device__ __forceinline__ unsigned cvt_pk_bf16(float lo, float hi) {
  unsigned r;
  asm("v_cvt_pk_bf16_f32 %0, %1, %2" : "=v"(r) : "v"(lo), "v"(hi));
  return r;
}
// v_cvt_pkrtz_f16_f32: pack 2 f32 -> 2 f16 (RTZ); return raw u32 payload
static __device__ __forceinline__ unsigned cvt_pk_f16(float lo, float hi) {
  return __builtin_bit_cast(unsigned, __builtin_amdgcn_cvt_pkrtz(lo, hi));
}
static __device__ __forceinline__ void plane_swap(unsigned& a, unsigned& b) {
  asm("v_permlane32_swap_b32 %0, %1" : "+v"(a), "+v"(b));
}
static __device__ __forceinline__ float xhalf_add(float x) {
  float a = x, b = x;
  asm("v_permlane32_swap_b32 %0, %1" : "+v"(a), "+v"(b));
  return a + b;  // own + partner(lane^32), valid in all 64 lanes
}
// packed dual-fp32 add (VOP3P, CDNA2+): 2 adds per instruction
static __device__ __forceinline__ f32x2 pk_add(f32x2 a, f32x2 b) {
  f32x2 d;
  asm("v_pk_add_f32 %0, %1, %2" : "=v"(d) : "v"(a), "v"(b));
  return d;
}
// C/D row formula for 32x32 MFMA (m74/m101): row = (r&3)+8*(r>>2)+4*hi
static __device__ __forceinline__ int rowf(int r, int hi) {
  return (r & 3) + 8 * (r >> 2) + 4 * hi;
}
static __device__ __forceinline__ bf16x8 pack8(const float* v) {
  unsigned p0 = cvt_pk_bf16(v[0], v[1]);
  unsigned p1 = cvt_pk_bf16(v[2], v[3]);
  unsigned p2 = cvt_pk_bf16(v[4], v[5]);
  unsigned p3 = cvt_pk_bf16(v[6], v[7]);
  return __builtin_bit_cast(bf16x8, (u32x4){p0, p1, p2, p3});
}

// ---------------- projection v5: 3-way block split + LDS-staged X ----------
// grid 1536 = which(3) x img(4) x l-tile(128). 4 waves x 1 o-tile of 32.
// X tile staged once in LDS (was loaded 4x, once per wave).
__global__ __launch_bounds__(256) void proj_kernel(
    const float* __restrict__ fct, const float* __restrict__ fpet,
    const float* __restrict__ wq, const float* __restrict__ bq,
    const float* __restrict__ wk, const float* __restrict__ bk,
    const float* __restrict__ wv, const float* __restrict__ bv,
    unsigned short* __restrict__ Qbf, unsigned short* __restrict__ Kbf,
    unsigned short* __restrict__ Vt, float* __restrict__ QT)
{
  __shared__ __align__(16) float Xs[64][36];            // 9.2 KB
  __shared__ __align__(16) unsigned short Tb[32][136];  // 8.7 KB

  int bid = blockIdx.x;
  int lt = bid & 127;
  int rest = bid >> 7;     // 0..11
  int mb = rest & 3;
  int which = rest >> 2;   // 0=Q 1=K 2=V
  int l0 = lt * 32;
  int b = mb & 1;
  const float* xb = (mb >= 2 ? fpet : fct) + (size_t)b * C_ * L_;

  int tid = threadIdx.x;
  int lane = tid & 63, wid = tid >> 6;
  int l31 = lane & 31, hi = lane >> 5;
  int od = wid * 32;

  // stage X[64][32] once, coalesced f32x4
  {
    int r = tid >> 2, c4 = tid & 3;
    const float* s = xb + (size_t)r * L_ + l0 + c4 * 8;
    f32x4 a0 = *(const f32x4*)(s);
    f32x4 a1 = *(const f32x4*)(s + 4);
    *(f32x4*)&Xs[r][c4 * 8] = a0;
    *(f32x4*)&Xs[r][c4 * 8 + 4] = a1;
  }
  __syncthreads();

  const float* W  = which == 0 ? wq : (which == 1 ? wk : wv);
  const float* Bs = which == 0 ? bq : (which == 1 ? bk : bv);

  const f32x16 Z = {0.f, 0.f, 0.f, 0.f, 0.f, 0.f, 0.f, 0.f,
                    0.f, 0.f, 0.f, 0.f, 0.f, 0.f, 0.f, 0.f};
  f32x16 acc = Z;
  #pragma unroll
  for (int ch = 0; ch < 4; ++ch) {
    float v[8], a[8];
    #pragma unroll
    for (int j = 0; j < 8; ++j)
      v[j] = Xs[ch * 16 + hi * 8 + j][l31];
    const float* wr = W + (size_t)(od + l31) * C_ + ch * 16 + hi * 8;
    #pragma unroll
    for (int j = 0; j < 8; ++j) a[j] = wr[j];
    acc = __builtin_amdgcn_mfma_f32_32x32x16_bf16(pack8(a), pack8(v), acc, 0, 0, 0);
  }

  if (which == 2) {
    #pragma unroll
    for (int r = 0; r < 16; ++r) {
      int o = od + rowf(r, hi);
      Vt[((size_t)mb * TD_ + o) * L_ + l0 + l31] = f2bf(acc[r] + Bs[o]);
    }
  } else {
    if (which == 0) {
      #pragma unroll
      for (int r = 0; r < 16; ++r) {
        int o = od + rowf(r, hi);
        QT[((size_t)mb * TD_ + o) * L_ + l0 + l31] = acc[r] + Bs[o];
      }
    }
    float sc = which == 0 ? SCALE_LOG2E : 1.0f;
    #pragma unroll
    for (int rg = 0; rg < 4; ++rg) {
      int cb = od + 8 * rg + 4 * hi;
      float y0 = (acc[rg * 4 + 0] + Bs[cb + 0]) * sc;
      float y1 = (acc[rg * 4 + 1] + Bs[cb + 1]) * sc;
      float y2 = (acc[rg * 4 + 2] + Bs[cb + 2]) * sc;
      float y3 = (acc[rg * 4 + 3] + Bs[cb + 3]) * sc;
      u32x2 pk = {cvt_pk_bf16(y0, y1), cvt_pk_bf16(y2, y3)};
      *(u32x2*)&Tb[l31][cb] = pk;
    }
    __syncthreads();
    unsigned short* dstg = which ? Kbf : Qbf;
    int row = tid >> 3, chunk = tid & 7;
    int h = chunk >> 1, d0 = (chunk & 1) * 16;
    u16x8 v0 = *(const u16x8*)&Tb[row][chunk * 16];
    u16x8 v1 = *(const u16x8*)&Tb[row][chunk * 16 + 8];
    size_t gb = (((size_t)mb * H_ + h) * L_ + l0 + row) * HD_ + d0;
    *(u16x8*)&dstg[gb] = v0;
    *(u16x8*)&dstg[gb + 8] = v1;
  }
}

// ---------------- flash cross-attention v8: r8 structure + pk_add + setprio -
// 4 waves/SIMD is the register roofline (128 unified VGPR+AGPR) — do NOT
// request more via launch_bounds (r9: forced 8/EU -> accumulator spill, 12x).
static __device__ __forceinline__ void softmax_pv(
    const f32x16& S, f32x2& lp2, f32x16& O, bf16x8 vc0, bf16x8 vc1)
{
  float p[16];
  #pragma unroll
  for (int i = 0; i < 16; ++i) p[i] = EXP2F(S[i]);

  // packed-pair sum: 8 pk_adds replace 16 scalar adds; lp2 folds at the end
  f32x2 q0 = pk_add((f32x2){p[0], p[1]}, (f32x2){p[2], p[3]});
  f32x2 q1 = pk_add((f32x2){p[4], p[5]}, (f32x2){p[6], p[7]});
  f32x2 q2 = pk_add((f32x2){p[8], p[9]}, (f32x2){p[10], p[11]});
  f32x2 q3 = pk_add((f32x2){p[12], p[13]}, (f32x2){p[14], p[15]});
  q0 = pk_add(q0, q1);
  q2 = pk_add(q2, q3);
  q0 = pk_add(q0, q2);
  lp2 = pk_add(lp2, q0);

  unsigned w0 = cvt_pk_bf16(p[0], p[1]);
  unsigned w1 = cvt_pk_bf16(p[2], p[3]);
  unsigned w2 = cvt_pk_bf16(p[4], p[5]);
  unsigned w3 = cvt_pk_bf16(p[6], p[7]);
  unsigned w4 = cvt_pk_bf16(p[8], p[9]);
  unsigned w5 = cvt_pk_bf16(p[10], p[11]);
  unsigned w6 = cvt_pk_bf16(p[12], p[13]);
  unsigned w7 = cvt_pk_bf16(p[14], p[15]);
  plane_swap(w0, w2);
  plane_swap(w1, w3);
  plane_swap(w4, w6);
  plane_swap(w5, w7);
  bf16x8 pf0 = __builtin_bit_cast(bf16x8, (u32x4){w0, w1, w2, w3});
  bf16x8 pf1 = __builtin_bit_cast(bf16x8, (u32x4){w4, w5, w6, w7});

  __builtin_amdgcn_s_setprio(1);
  O = __builtin_amdgcn_mfma_f32_32x32x16_bf16(vc0, pf0, O, 0, 0, 0);
  O = __builtin_amdgcn_mfma_f32_32x32x16_bf16(vc1, pf1, O, 0, 0, 0);
  __builtin_amdgcn_s_setprio(0);
}

__global__ __launch_bounds__(256, 4) void attn_kernel(
    const unsigned short* __restrict__ Qbf, const unsigned short* __restrict__ Kbf,
    const unsigned short* __restrict__ Vt, const float* __restrict__ QT,
    unsigned short* __restrict__ Fh, unsigned short* __restrict__ Fl)
{
  __shared__ __align__(16) unsigned Obuf[4][64][17];  // fp16x2 packs, 17.4 KB
  __shared__ float lbuf[4][64];                       // 1 KB

  int bid = blockIdx.x;
  int x = bid & 7, local = bid >> 3;
  int g = 2 * x + (local & 1);  // XCD x serves only head-groups {2x, 2x+1}
  int qg = local >> 1;
  int h = g & 3, b = (g >> 2) & 1, dir = g >> 3;

  int lane = threadIdx.x & 63, wid = threadIdx.x >> 6;
  int l31 = lane & 31, hi = lane >> 5;
  int q0 = qg * 64;
  int qmb = dir * B_ + b, kmb = (1 - dir) * B_ + b;
  int k0 = wid * 1024;  // this wave's k-range

  // Q B-frags: direct bf16, pre-scaled at projection
  const unsigned short* qbase = Qbf + (size_t)(qmb * H_ + h) * L_ * HD_;
  bf16x8 qb[2][2];
  #pragma unroll
  for (int s = 0; s < 2; ++s)
    #pragma unroll
    for (int c = 0; c < 2; ++c)
      qb[s][c] = *(const bf16x8*)(qbase + (q0 + s * 32 + l31) * HD_ + c * 16 + hi * 8);

  const unsigned short* kp =
      Kbf + (size_t)(kmb * H_ + h) * L_ * HD_ + (k0 + l31) * HD_ + hi * 8;
  const unsigned short* vp =
      Vt + (size_t)(kmb * TD_ + h * HD_ + l31) * L_ + k0 + hi * 8;

  const f32x16 Z = {0.f, 0.f, 0.f, 0.f, 0.f, 0.f, 0.f, 0.f,
                    0.f, 0.f, 0.f, 0.f, 0.f, 0.f, 0.f, 0.f};
  f32x16 Oa[2] = {Z, Z};
  f32x2 lp2[2] = {(f32x2){0.f, 0.f}, (f32x2){0.f, 0.f}};

  bf16x8 kc0 = *(const bf16x8*)(kp);
  bf16x8 kc1 = *(const bf16x8*)(kp + 16);
  bf16x8 vc0 = *(const bf16x8*)(vp);
  bf16x8 vc1 = *(const bf16x8*)(vp + 16);

  #pragma unroll 4
  for (int t = 0; t < 32; ++t) {  // 32 tiles of 32 kk; depth-1 prefetch
    bf16x8 kn0 = *(const bf16x8*)(kp + (t + 1) * 1024);
    bf16x8 kn1 = *(const bf16x8*)(kp + (t + 1) * 1024 + 16);
    bf16x8 vn0 = *(const bf16x8*)(vp + (t + 1) * 32);
    bf16x8 vn1 = *(const bf16x8*)(vp + (t + 1) * 32 + 16);
    #pragma unroll
    for (int s = 0; s < 2; ++s) {
      __builtin_amdgcn_s_setprio(1);
      f32x16 S = __builtin_amdgcn_mfma_f32_32x32x16_bf16(kc0, qb[s][0], Z, 0, 0, 0);
      S = __builtin_amdgcn_mfma_f32_32x32x16_bf16(kc1, qb[s][1], S, 0, 0, 0);
      __builtin_amdgcn_s_setprio(0);
      softmax_pv(S, lp2[s], Oa[s], vc0, vc1);
    }
    kc0 = kn0; kc1 = kn1; vc0 = vn0; vc1 = vn1;
  }

  // ---- cross-wave merge, fp16-packed partials ----
  float lpa = xhalf_add(lp2[0][0] + lp2[0][1]);
  float lpb = xhalf_add(lp2[1][0] + lp2[1][1]);
  if (hi == 0) {
    lbuf[wid][l31] = lpa;
    lbuf[wid][32 + l31] = lpb;
  }
  #pragma unroll
  for (int s = 0; s < 2; ++s)
    #pragma unroll
    for (int r = 0; r < 16; r += 2) {  // even r: rowf(r+1)==rowf(r)+1
      unsigned pk2 = cvt_pk_f16(Oa[s][r], Oa[s][r + 1]);
      int d2 = ((r & 3) >> 1) + 4 * (r >> 2) + 2 * hi;
      Obuf[wid][s * 32 + l31][d2] = pk2;
    }
  __syncthreads();

  int lane_ = threadIdx.x & 63;
  float T = (lbuf[0][lane_] + lbuf[1][lane_]) + (lbuf[2][lane_] + lbuf[3][lane_]);
  float inv = 1.0f / T;
  const float* qtp = QT + ((size_t)qmb * TD_ + h * HD_) * L_ + q0 + lane_;
  float vals[8];
  #pragma unroll
  for (int jp = 0; jp < 4; ++jp) {
    float se = 0.f, so = 0.f;
    #pragma unroll
    for (int w = 0; w < 4; ++w) {
      f16x2 v = __builtin_bit_cast(f16x2, Obuf[w][lane_][wid * 4 + jp]);
      se += (float)v[0];
      so += (float)v[1];
    }
    int dd = wid * 8 + jp * 2;
    vals[jp * 2]     = (se * inv + qtp[(size_t)dd * L_]) * 0.5f;
    vals[jp * 2 + 1] = (so * inv + qtp[(size_t)(dd + 1) * L_]) * 0.5f;
  }
  __syncthreads();

  // reuse Obuf region as bf16 hi/lo staging, then coalesced 16B stores
  unsigned (*Sb)[64][17] = (unsigned (*)[64][17])Obuf;
  #pragma unroll
  for (int jp = 0; jp < 4; ++jp) {
    float v0 = vals[jp * 2], v1 = vals[jp * 2 + 1];
    float h0 = bf2f(f2bf(v0)), h1 = bf2f(f2bf(v1));
    Sb[0][lane_][wid * 4 + jp] = cvt_pk_bf16(v0, v1);            // hi (RNE)
    Sb[1][lane_][wid * 4 + jp] = cvt_pk_bf16(v0 - h0, v1 - h1);  // lo residual
  }
  __syncthreads();
  int q = threadIdx.x >> 2, dq = threadIdx.x & 3;
  u32x4 vh = *(const u32x4*)&Sb[0][q][dq * 4];
  u32x4 vl = *(const u32x4*)&Sb[1][q][dq * 4];
  size_t gb = ((size_t)qmb * L_ + q0 + q) * TD_ + h * HD_ + dq * 8;
  *(u16x8*)&Fh[gb] = __builtin_bit_cast(u16x8, vh);
  *(u16x8*)&Fl[gb] = __builtin_bit_cast(u16x8, vl);
}

// ---------------- epilogue v4 (unchanged, passing) ----------------
__global__ __launch_bounds__(256) void epi_kernel(
    const float* __restrict__ fct, const float* __restrict__ fpet,
    const float* __restrict__ wo, const float* __restrict__ bo,
    const unsigned short* __restrict__ Fh, const unsigned short* __restrict__ Fl,
    float* __restrict__ out)
{
  __shared__ __align__(16) unsigned short Gh[32][136], Gl[32][136];  // 17.4 KB
  __shared__ __align__(16) float red[2][32][33];                     // 8.4 KB

  int bid = blockIdx.x;
  int lt = bid & 127, im = bid >> 7;  // im = dir*B + b
  int b = im & 1, d = im >> 1;
  int l0 = lt * 32;
  int lr = l0 >> 7, col0 = l0 & 127;

  int tid = threadIdx.x;
  int lane = tid & 63, wid = tid >> 6;
  int l31 = lane & 31, hi = lane >> 5;
  int mt = wid & 1, kh = wid >> 1;
  int c0 = mt * 32;

  bf16x8 Ah[4], Al[4];
  #pragma unroll
  for (int ch = 0; ch < 4; ++ch) {
    const float* wr = wo + (size_t)(c0 + l31) * TD_ + (kh * 4 + ch) * 16 + hi * 8;
    float ah[8], al[8];
    #pragma unroll
    for (int j = 0; j < 8; ++j) {
      float v = wr[j];
      float hf = bf2f(f2bf(v));
      ah[j] = hf;
      al[j] = v - hf;
    }
    Ah[ch] = pack8(ah);
    Al[ch] = pack8(al);
  }

  {
    int o = tid & 127, half = tid >> 7;
    size_t src = ((size_t)im * L_ + o * 32 + lr) * TD_ + col0 + half * 16;
    u16x8 ha = *(const u16x8*)&Fh[src];
    u16x8 hb = *(const u16x8*)&Fh[src + 8];
    u16x8 la = *(const u16x8*)&Fl[src];
    u16x8 lb = *(const u16x8*)&Fl[src + 8];
    #pragma unroll
    for (int j = 0; j < 8; ++j) {
      Gh[half * 16 + j][o] = ha[j];
      Gl[half * 16 + j][o] = la[j];
    }
    #pragma unroll
    for (int j = 0; j < 8; ++j) {
      Gh[half * 16 + 8 + j][o] = hb[j];
      Gl[half * 16 + 8 + j][o] = lb[j];
    }
  }
  __syncthreads();

  const f32x16 Z = {0.f, 0.f, 0.f, 0.f, 0.f, 0.f, 0.f, 0.f,
                    0.f, 0.f, 0.f, 0.f, 0.f, 0.f, 0.f, 0.f};
  f32x16 acc = Z;
  #pragma unroll
  for (int ch = 0; ch < 4; ++ch) {
    int ko = (kh * 4 + ch) * 16 + hi * 8;
    bf16x8 Bh = *(const bf16x8*)&Gh[l31][ko];
    bf16x8 Bl = *(const bf16x8*)&Gl[l31][ko];
    acc = __builtin_amdgcn_mfma_f32_32x32x16_bf16(Ah[ch], Bh, acc, 0, 0, 0);
    acc = __builtin_amdgcn_mfma_f32_32x32x16_bf16(Ah[ch], Bl, acc, 0, 0, 0);
    acc = __builtin_amdgcn_mfma_f32_32x32x16_bf16(Al[ch], Bh, acc, 0, 0, 0);
  }

  if (kh == 1) {
    #pragma unroll
    for (int r = 0; r < 16; ++r) red[mt][rowf(r, hi)][l31] = acc[r];
  }
  __syncthreads();
  if (kh == 0) {
    const float* feat = (d ? fpet : fct) + (size_t)b * C_ * L_;
    float* ob = out + (size_t)im * C_ * L_;
    int l = l0 + l31;
    #pragma unroll
    for (int r = 0; r < 16; ++r) {
      int row = rowf(r, hi);
      int c = c0 + row;
      float v = acc[r] + red[mt][row][l31];
      ob[(size_t)c * L_ + l] = feat[(size_t)c * L_ + l] + bo[c] + v;
    }
  }
}

extern "C" void kernel_launch(void* const* d_in, const int* in_sizes, int n_in,
                              void* d_out, int out_size, void* d_ws, size_t ws_size,
                              hipStream_t stream)
{
  const float* fct  = (const float*)d_in[0];
  const float* fpet = (const float*)d_in[1];
  const float* wq = (const float*)d_in[2];
  const float* bq = (const float*)d_in[3];
  const float* wk = (const float*)d_in[4];
  const float* bk = (const float*)d_in[5];
  const float* wv = (const float*)d_in[6];
  const float* bv = (const float*)d_in[7];
  const float* wo = (const float*)d_in[8];
  const float* bo = (const float*)d_in[9];
  float* out = (float*)d_out;

  // ws: Qbf,Kbf,Vt (2M ushorts each, 12MB) + QT (2M f32, 8MB) + Fh,Fl (2M
  // ushorts each, 8MB) = 28MB
  unsigned short* Qbf = (unsigned short*)d_ws;
  unsigned short* Kbf = Qbf + 2097152;
  unsigned short* Vt  = Kbf + 2097152;
  float* QT = (float*)(Vt + 2097152);
  unsigned short* Fh = (unsigned short*)(QT + 2097152);
  unsigned short* Fl = Fh + 2097152;

  proj_kernel<<<1536, 256, 0, stream>>>(fct, fpet, wq, bq, wk, bk, wv, bv,
                                        Qbf, Kbf, Vt, QT);
  attn_kernel<<<1024, 256, 0, stream>>>(Qbf, Kbf, Vt, QT, Fh, Fl);
  epi_kernel<<<512, 256, 0, stream>>>(fct, fpet, wo, bo, Fh, Fl, out);
}